// Round 1
// baseline (1642.111 us; speedup 1.0000x reference)
//
#include <hip/hip_runtime.h>

#define N_NODES 50000
#define N_EDGES 1600000

typedef _Float16 f16x8 __attribute__((ext_vector_type(8)));
typedef float f32x4 __attribute__((ext_vector_type(4)));

// ---------------------------------------------------------------------------
// prep_weights: build f16 weight images in ws, transposed ([n][k]) and
// 16B-chunk XOR-swizzled (chunk' = chunk ^ (n&7)) so that (a) LDS staging in
// the edge kernel is a flat coalesced float4 copy and (b) MFMA B-fragment
// loads are conflict-free ds_read_b128.
// W1img: [128 n][64 k] (Wf1 is 50x128, zero-padded K->64).  W2img: [128][128].
// ---------------------------------------------------------------------------
__global__ void prep_weights(const float* __restrict__ Wf1,
                             const float* __restrict__ Wf2,
                             _Float16* __restrict__ W1img,
                             _Float16* __restrict__ W2img) {
    int i = blockIdx.x * 256 + threadIdx.x;
    if (i < 8192) {                       // W1img
        int n = i >> 6, k = i & 63;
        float v = (k < 50) ? Wf1[k * 128 + n] : 0.0f;
        W1img[n * 64 + (((k >> 3) ^ (n & 7)) << 3) + (k & 7)] = (_Float16)v;
    }
    if (i < 16384) {                      // W2img
        int n = i >> 7, k = i & 127;
        W2img[n * 128 + (((k >> 3) ^ (n & 7)) << 3) + (k & 7)] =
            (_Float16)Wf2[k * 128 + n];
    }
}

// ---------------------------------------------------------------------------
// hv_kernel (fp32): hv = feat @ W_in2f.  16 rows/block; A staged transposed
// in LDS so the 8-row strip loads are two float4 broadcasts per k.
// ---------------------------------------------------------------------------
__global__ __launch_bounds__(256) void hv_kernel(const float* __restrict__ feat,
                                                 const float* __restrict__ W,
                                                 float* __restrict__ hv) {
    __shared__ float sAT[128 * 20];       // [k][row], pad 20 for bank spread
    const int tid = threadIdx.x;
    const int row0 = blockIdx.x * 16;
    for (int t = 0; t < 8; ++t) {
        int flat = tid + 256 * t;
        int rr = flat >> 7, k = flat & 127;
        sAT[k * 20 + rr] = feat[(row0 + rr) * 128 + k];
    }
    __syncthreads();
    const int c = tid & 127, rh = tid >> 7;
    float acc[8] = {0, 0, 0, 0, 0, 0, 0, 0};
    for (int k = 0; k < 128; ++k) {
        float wval = W[k * 128 + c];
        const float4 alo = *(const float4*)&sAT[k * 20 + rh * 8];
        const float4 ahi = *(const float4*)&sAT[k * 20 + rh * 8 + 4];
        acc[0] += alo.x * wval; acc[1] += alo.y * wval;
        acc[2] += alo.z * wval; acc[3] += alo.w * wval;
        acc[4] += ahi.x * wval; acc[5] += ahi.y * wval;
        acc[6] += ahi.z * wval; acc[7] += ahi.w * wval;
    }
    for (int r = 0; r < 8; ++r)
        hv[(row0 + rh * 8 + r) * 128 + c] = acc[r];
}

// ---------------------------------------------------------------------------
// edge_kernel: per 128-edge tile:
//   GEMM1 (f16 MFMA): x1 = fij @ Wf1   (K = 50 zero-padded to 64)
//   t = swish(x1 + bf1)  -> LDS (A-fragment-compatible swizzled row-major)
//   GEMM2 (f16 MFMA): he = t @ Wf2
//   he = (he + bf2) * C(rij);  m = hv[src] * he;  atomicAdd(agg[dst], m)
// LDS: [sA1 16K | sW1 16K] overlaid by sT 32K after GEMM1; sW2 32K. = 64 KB.
// MFMA 16x16x32_f16 layouts (verified m89/m91/m120):
//   A: m = lane&15, k = (lane>>4)*8 + j;  B: k = (lane>>4)*8 + j, n = lane&15
//   D: row = (lane>>4)*4 + r, col = lane&15
// ---------------------------------------------------------------------------
__global__ __launch_bounds__(256, 2) void edge_kernel(
        const float* __restrict__ fij, const float* __restrict__ rij,
        const int* __restrict__ srcv, const int* __restrict__ dstv,
        const float* __restrict__ hv,
        const _Float16* __restrict__ W1img, const _Float16* __restrict__ W2img,
        const float* __restrict__ bf1, const float* __restrict__ bf2,
        float* __restrict__ agg) {
    __shared__ __align__(16) char smem[65536];
    _Float16* sA1 = (_Float16*)smem;              // [128][64]
    _Float16* sW1 = (_Float16*)(smem + 16384);    // [128][64]
    _Float16* sT  = (_Float16*)smem;              // [128][128] overlays sA1+sW1
    _Float16* sW2 = (_Float16*)(smem + 32768);    // [128][128]

    const int tid = threadIdx.x;
    const int lane = tid & 63;
    const int wv = tid >> 6;          // wave 0..3 -> edge rows [wv*32, wv*32+32)
    const int l15 = lane & 15;
    const int q = lane >> 4;
    const int e0 = blockIdx.x * 128;

    // ---- stage weight images: flat coalesced float4 copies ----
    {
        const float4* s1 = (const float4*)W1img;
        float4* d1 = (float4*)sW1;
        for (int t = 0; t < 4; ++t) d1[tid + 256 * t] = s1[tid + 256 * t];
        const float4* s2 = (const float4*)W2img;
        float4* d2 = (float4*)sW2;
        for (int t = 0; t < 8; ++t) d2[tid + 256 * t] = s2[tid + 256 * t];
    }
    // ---- stage fij tile -> sA1 (f32->f16, swizzled), coalesced reads ----
    for (int t = 0; t < 32; ++t) {
        int flat = tid + 256 * t;             // 0..8191
        int row = flat >> 6, k = flat & 63;
        float v = (k < 50) ? fij[(e0 + row) * 50 + k] : 0.0f;
        sA1[row * 64 + (((k >> 3) ^ (row & 7)) << 3) + (k & 7)] = (_Float16)v;
    }
    // ---- per-lane row metadata (this lane owns D-rows q*4+r of 2 row-tiles)
    float C8[8]; int s8[8], d8[8];
    for (int mbl = 0; mbl < 2; ++mbl)
        for (int r = 0; r < 4; ++r) {
            int i8 = mbl * 4 + r;
            int e = e0 + wv * 32 + mbl * 16 + q * 4 + r;
            float rv = rij[e];
            C8[i8] = (rv < 5.0f) ? 0.5f * (__cosf(0.6283185307179586f * rv) + 1.0f) : 0.0f;
            s8[i8] = srcv[e] * 128;
            d8[i8] = dstv[e] * 128;
        }
    float b1v[8], b2v[8];
    for (int nb = 0; nb < 8; ++nb) {
        b1v[nb] = bf1[nb * 16 + l15];
        b2v[nb] = bf2[nb * 16 + l15];
    }
    __syncthreads();

    // ---- GEMM1: [32 x 64] x [64 x 128] per wave ----
    f32x4 acc[2][8];
    for (int mbl = 0; mbl < 2; ++mbl)
        for (int nb = 0; nb < 8; ++nb) acc[mbl][nb] = (f32x4){0.f, 0.f, 0.f, 0.f};
    for (int ks = 0; ks < 2; ++ks) {
        f16x8 a[2], b[8];
        const int c = ks * 4 + q;
        for (int mbl = 0; mbl < 2; ++mbl) {
            int row = wv * 32 + mbl * 16 + l15;
            a[mbl] = *(const f16x8*)&sA1[row * 64 + ((c ^ (row & 7)) << 3)];
        }
        for (int nb = 0; nb < 8; ++nb) {
            int n = nb * 16 + l15;
            b[nb] = *(const f16x8*)&sW1[n * 64 + ((c ^ (n & 7)) << 3)];
        }
        for (int mbl = 0; mbl < 2; ++mbl)
            for (int nb = 0; nb < 8; ++nb)
                acc[mbl][nb] = __builtin_amdgcn_mfma_f32_16x16x32_f16(
                    a[mbl], b[nb], acc[mbl][nb], 0, 0, 0);
    }
    __syncthreads();   // all waves done reading sA1/sW1 before sT overlays them

    // ---- epilogue1: t = swish(x1 + bf1) -> sT ----
    for (int mbl = 0; mbl < 2; ++mbl)
        for (int nb = 0; nb < 8; ++nb)
            for (int r = 0; r < 4; ++r) {
                float x = acc[mbl][nb][r] + b1v[nb];
                float tt = x / (1.0f + __expf(-x));
                int row = wv * 32 + mbl * 16 + q * 4 + r;
                int col = nb * 16 + l15;
                sT[row * 128 + (((col >> 3) ^ (row & 7)) << 3) + (col & 7)] = (_Float16)tt;
            }
    __syncthreads();

    // ---- GEMM2: [32 x 128] x [128 x 128] per wave ----
    for (int mbl = 0; mbl < 2; ++mbl)
        for (int nb = 0; nb < 8; ++nb) acc[mbl][nb] = (f32x4){0.f, 0.f, 0.f, 0.f};
    for (int ks = 0; ks < 4; ++ks) {
        f16x8 a[2], b[8];
        const int c = ks * 4 + q;   // chunk 0..15; swizzle xors low 3 bits only
        for (int mbl = 0; mbl < 2; ++mbl) {
            int row = wv * 32 + mbl * 16 + l15;
            a[mbl] = *(const f16x8*)&sT[row * 128 + ((c ^ (row & 7)) << 3)];
        }
        for (int nb = 0; nb < 8; ++nb) {
            int n = nb * 16 + l15;
            b[nb] = *(const f16x8*)&sW2[n * 128 + ((c ^ (n & 7)) << 3)];
        }
        for (int mbl = 0; mbl < 2; ++mbl)
            for (int nb = 0; nb < 8; ++nb)
                acc[mbl][nb] = __builtin_amdgcn_mfma_f32_16x16x32_f16(
                    a[mbl], b[nb], acc[mbl][nb], 0, 0, 0);
    }

    // ---- epilogue2: cutoff, hv gather, atomic scatter-add ----
    for (int mbl = 0; mbl < 2; ++mbl)
        for (int r = 0; r < 4; ++r) {
            int i8 = mbl * 4 + r;
            float Cr = C8[i8];
            int sb = s8[i8], db = d8[i8];
            for (int nb = 0; nb < 8; ++nb) {
                int col = nb * 16 + l15;
                float he = (acc[mbl][nb][r] + b2v[nb]) * Cr;
                float m = hv[sb + col] * he;
                atomicAdd(&agg[db + col], m);
            }
        }
}

// ---------------------------------------------------------------------------
// out_kernel (fp32): out = swish(agg @ Wm1 + bm1) @ Wm2 + bm2, fused.
// ---------------------------------------------------------------------------
__global__ __launch_bounds__(256) void out_kernel(const float* __restrict__ agg,
                                                  const float* __restrict__ Wm1,
                                                  const float* __restrict__ bm1,
                                                  const float* __restrict__ Wm2,
                                                  const float* __restrict__ bm2,
                                                  float* __restrict__ out) {
    __shared__ float sAT[128 * 20];
    __shared__ float sTT[128 * 20];
    const int tid = threadIdx.x;
    const int row0 = blockIdx.x * 16;
    for (int t = 0; t < 8; ++t) {
        int flat = tid + 256 * t;
        int rr = flat >> 7, k = flat & 127;
        sAT[k * 20 + rr] = agg[(row0 + rr) * 128 + k];
    }
    __syncthreads();
    const int c = tid & 127, rh = tid >> 7;
    float acc[8] = {0, 0, 0, 0, 0, 0, 0, 0};
    for (int k = 0; k < 128; ++k) {
        float wval = Wm1[k * 128 + c];
        const float4 alo = *(const float4*)&sAT[k * 20 + rh * 8];
        const float4 ahi = *(const float4*)&sAT[k * 20 + rh * 8 + 4];
        acc[0] += alo.x * wval; acc[1] += alo.y * wval;
        acc[2] += alo.z * wval; acc[3] += alo.w * wval;
        acc[4] += ahi.x * wval; acc[5] += ahi.y * wval;
        acc[6] += ahi.z * wval; acc[7] += ahi.w * wval;
    }
    float bm1c = bm1[c];
    for (int r = 0; r < 8; ++r) {
        float x = acc[r] + bm1c;
        sTT[c * 20 + rh * 8 + r] = x / (1.0f + __expf(-x));
    }
    __syncthreads();
    float acc2[8] = {0, 0, 0, 0, 0, 0, 0, 0};
    for (int k = 0; k < 128; ++k) {
        float wval = Wm2[k * 128 + c];
        const float4 alo = *(const float4*)&sTT[k * 20 + rh * 8];
        const float4 ahi = *(const float4*)&sTT[k * 20 + rh * 8 + 4];
        acc2[0] += alo.x * wval; acc2[1] += alo.y * wval;
        acc2[2] += alo.z * wval; acc2[3] += alo.w * wval;
        acc2[4] += ahi.x * wval; acc2[5] += ahi.y * wval;
        acc2[6] += ahi.z * wval; acc2[7] += ahi.w * wval;
    }
    float bm2c = bm2[c];
    for (int r = 0; r < 8; ++r)
        out[(row0 + rh * 8 + r) * 128 + c] = acc2[r] + bm2c;
}

// ---------------------------------------------------------------------------
extern "C" void kernel_launch(void* const* d_in, const int* in_sizes, int n_in,
                              void* d_out, int out_size, void* d_ws, size_t ws_size,
                              hipStream_t stream) {
    const float* feat   = (const float*)d_in[0];
    const float* fij    = (const float*)d_in[1];
    const float* rij    = (const float*)d_in[2];
    const int*   srcv   = (const int*)d_in[3];
    const int*   dstv   = (const int*)d_in[4];
    const float* W_in2f = (const float*)d_in[5];
    const float* Wf1    = (const float*)d_in[6];
    const float* bf1    = (const float*)d_in[7];
    const float* Wf2    = (const float*)d_in[8];
    const float* bf2    = (const float*)d_in[9];
    const float* Wm1    = (const float*)d_in[10];
    const float* bm1    = (const float*)d_in[11];
    const float* Wm2    = (const float*)d_in[12];
    const float* bm2    = (const float*)d_in[13];
    float* out = (float*)d_out;

    char* ws = (char*)d_ws;
    float*    hv    = (float*)ws;                          // 25.6 MB
    float*    agg   = (float*)(ws + 25600000);             // 25.6 MB
    _Float16* W1img = (_Float16*)(ws + 51200000);          // 16 KB
    _Float16* W2img = (_Float16*)(ws + 51200000 + 16384);  // 32 KB

    hipMemsetAsync(agg, 0, (size_t)N_NODES * 128 * sizeof(float), stream);
    prep_weights<<<64, 256, 0, stream>>>(Wf1, Wf2, W1img, W2img);
    hv_kernel<<<3125, 256, 0, stream>>>(feat, W_in2f, hv);
    edge_kernel<<<12500, 256, 0, stream>>>(fij, rij, srcv, dstv, hv,
                                           W1img, W2img, bf1, bf2, agg);
    out_kernel<<<3125, 256, 0, stream>>>(agg, Wm1, bm1, Wm2, bm2, out);
}

// Round 2
// 1481.556 us; speedup vs baseline: 1.1084x; 1.1084x over previous
//
#include <hip/hip_runtime.h>

#define N_NODES 50000
#define N_EDGES 1600000

typedef _Float16 f16x8 __attribute__((ext_vector_type(8)));
typedef float f32x4 __attribute__((ext_vector_type(4)));

// ---------------------------------------------------------------------------
// prep_weights: f16 weight images, transposed ([n][k]) and 16B-chunk
// XOR-swizzled (chunk' = chunk ^ (n&7)) -> flat coalesced LDS staging and
// conflict-free ds_read_b128 fragment loads.
// W1img: [128 n][64 k] (Wf1 50x128, K zero-padded to 64).  W2img: [128][128].
// ---------------------------------------------------------------------------
__global__ void prep_weights(const float* __restrict__ Wf1,
                             const float* __restrict__ Wf2,
                             _Float16* __restrict__ W1img,
                             _Float16* __restrict__ W2img) {
    int i = blockIdx.x * 256 + threadIdx.x;
    if (i < 8192) {
        int n = i >> 6, k = i & 63;
        float v = (k < 50) ? Wf1[k * 128 + n] : 0.0f;
        W1img[n * 64 + (((k >> 3) ^ (n & 7)) << 3) + (k & 7)] = (_Float16)v;
    }
    if (i < 16384) {
        int n = i >> 7, k = i & 127;
        W2img[n * 128 + (((k >> 3) ^ (n & 7)) << 3) + (k & 7)] =
            (_Float16)Wf2[k * 128 + n];
    }
}

// ---------------------------------------------------------------------------
// Counting sort by dst: hist -> exclusive scan (in place, becomes cursor) ->
// scatter packed {eid, src, dst, rij} records.
// ---------------------------------------------------------------------------
__global__ void hist_kernel(const int* __restrict__ dstv, int* __restrict__ cnt) {
    int e = blockIdx.x * 256 + threadIdx.x;
    if (e < N_EDGES) atomicAdd(&cnt[dstv[e]], 1);
}

__global__ __launch_bounds__(1024) void scan_kernel(int* __restrict__ cnt) {
    __shared__ int buf[1024];
    const int tid = threadIdx.x;
    int base = 0;
    for (int c0 = 0; c0 < N_NODES; c0 += 1024) {
        int i = c0 + tid;
        int x = (i < N_NODES) ? cnt[i] : 0;
        buf[tid] = x;
        __syncthreads();
        for (int off = 1; off < 1024; off <<= 1) {
            int v = (tid >= off) ? buf[tid - off] : 0;
            __syncthreads();
            buf[tid] += v;
            __syncthreads();
        }
        if (i < N_NODES) cnt[i] = base + buf[tid] - x;   // exclusive
        base += buf[1023];
        __syncthreads();
    }
}

__global__ void scatter_kernel(const int* __restrict__ dstv,
                               const int* __restrict__ srcv,
                               const float* __restrict__ rij,
                               int* __restrict__ cursor,
                               int4* __restrict__ meta) {
    int e = blockIdx.x * 256 + threadIdx.x;
    if (e < N_EDGES) {
        int d = dstv[e];
        int pos = atomicAdd(&cursor[d], 1);
        meta[pos] = make_int4(e, srcv[e], d, __float_as_int(rij[e]));
    }
}

// ---------------------------------------------------------------------------
// hv_kernel (fp32 compute, f16 store): hv = feat @ W_in2f.
// ---------------------------------------------------------------------------
__global__ __launch_bounds__(256) void hv_kernel(const float* __restrict__ feat,
                                                 const float* __restrict__ W,
                                                 _Float16* __restrict__ hvh) {
    __shared__ float sAT[128 * 20];
    const int tid = threadIdx.x;
    const int row0 = blockIdx.x * 16;
    for (int t = 0; t < 8; ++t) {
        int flat = tid + 256 * t;
        int rr = flat >> 7, k = flat & 127;
        sAT[k * 20 + rr] = feat[(row0 + rr) * 128 + k];
    }
    __syncthreads();
    const int c = tid & 127, rh = tid >> 7;
    float acc[8] = {0, 0, 0, 0, 0, 0, 0, 0};
    for (int k = 0; k < 128; ++k) {
        float wval = W[k * 128 + c];
        const float4 alo = *(const float4*)&sAT[k * 20 + rh * 8];
        const float4 ahi = *(const float4*)&sAT[k * 20 + rh * 8 + 4];
        acc[0] += alo.x * wval; acc[1] += alo.y * wval;
        acc[2] += alo.z * wval; acc[3] += alo.w * wval;
        acc[4] += ahi.x * wval; acc[5] += ahi.y * wval;
        acc[6] += ahi.z * wval; acc[7] += ahi.w * wval;
    }
    for (int r = 0; r < 8; ++r)
        hvh[(row0 + rh * 8 + r) * 128 + c] = (_Float16)acc[r];
}

// ---------------------------------------------------------------------------
// edge_kernel over dst-sorted edges. Per 128-edge tile:
//   GEMM1 (f16 MFMA): x1 = fij[eid] @ Wf1 ; t = swish(x1+bf1) -> sT
//   GEMM2 (f16 MFMA): he = t @ Wf2
//   m = hv[src] * (he+bf2)*C(rij) -> sM (fp32, swizzled)
//   segmented run-reduction per column over sorted dst -> few atomicAdd
// LDS: phase A [sA1 16K|sW1 16K|sW2 32K]; phase B sT overlays [0,32K);
//      phase C sM (fp32 64K) overlays all. + sMeta 2K.
// MFMA 16x16x32_f16 layouts (verified):
//   A: m=lane&15, k=(lane>>4)*8+j;  D: row=(lane>>4)*4+r, col=lane&15
// ---------------------------------------------------------------------------
__global__ __launch_bounds__(256, 2) void edge_kernel(
        const float* __restrict__ fij, const _Float16* __restrict__ hvh,
        const _Float16* __restrict__ W1img, const _Float16* __restrict__ W2img,
        const float* __restrict__ bf1, const float* __restrict__ bf2,
        const int4* __restrict__ meta, float* __restrict__ agg) {
    __shared__ __align__(16) char smem[65536];
    __shared__ __align__(16) int4 sMeta[128];
    _Float16* sA1 = (_Float16*)smem;              // [128][64]
    _Float16* sW1 = (_Float16*)(smem + 16384);    // [128][64]
    _Float16* sT  = (_Float16*)smem;              // [128][128] overlays sA1+sW1
    _Float16* sW2 = (_Float16*)(smem + 32768);    // [128][128]
    float*    sM  = (float*)smem;                 // [128][128] fp32, phase C

    const int tid = threadIdx.x;
    const int lane = tid & 63;
    const int wv = tid >> 6;          // wave -> edge rows [wv*32, wv*32+32)
    const int l15 = lane & 15;
    const int q = lane >> 4;
    const int e0 = blockIdx.x * 128;

    // ---- stage sorted metadata (contiguous) + weight images ----
    if (tid < 128) sMeta[tid] = meta[e0 + tid];
    {
        const float4* s1 = (const float4*)W1img;
        float4* d1 = (float4*)sW1;
        for (int t = 0; t < 4; ++t) d1[tid + 256 * t] = s1[tid + 256 * t];
        const float4* s2 = (const float4*)W2img;
        float4* d2 = (float4*)sW2;
        for (int t = 0; t < 8; ++t) d2[tid + 256 * t] = s2[tid + 256 * t];
    }
    __syncthreads();   // sMeta visible for fij gather

    // ---- stage fij rows (gathered by eid) -> sA1 (f32->f16, swizzled) ----
    for (int t = 0; t < 32; ++t) {
        int flat = tid + 256 * t;             // 0..8191
        int row = flat >> 6, k = flat & 63;
        int eid = sMeta[row].x;               // wave-uniform broadcast
        float v = (k < 50) ? fij[(long)eid * 50 + k] : 0.0f;
        sA1[row * 64 + (((k >> 3) ^ (row & 7)) << 3) + (k & 7)] = (_Float16)v;
    }
    // ---- per-lane row metadata (lane owns D-rows q*4+r of 2 row-tiles) ----
    float C8[8]; int s8[8];
    for (int mbl = 0; mbl < 2; ++mbl)
        for (int r = 0; r < 4; ++r) {
            int i8 = mbl * 4 + r;
            int4 mm = sMeta[wv * 32 + mbl * 16 + q * 4 + r];
            float rv = __int_as_float(mm.w);
            C8[i8] = (rv < 5.0f) ? 0.5f * (__cosf(0.6283185307179586f * rv) + 1.0f) : 0.0f;
            s8[i8] = mm.y * 128;
        }
    float b1v[8], b2v[8];
    for (int nb = 0; nb < 8; ++nb) {
        b1v[nb] = bf1[nb * 16 + l15];
        b2v[nb] = bf2[nb * 16 + l15];
    }
    __syncthreads();

    // ---- GEMM1: [32 x 64] x [64 x 128] per wave ----
    f32x4 acc[2][8];
    for (int mbl = 0; mbl < 2; ++mbl)
        for (int nb = 0; nb < 8; ++nb) acc[mbl][nb] = (f32x4){0.f, 0.f, 0.f, 0.f};
    for (int ks = 0; ks < 2; ++ks) {
        f16x8 a[2], b[8];
        const int c = ks * 4 + q;
        for (int mbl = 0; mbl < 2; ++mbl) {
            int row = wv * 32 + mbl * 16 + l15;
            a[mbl] = *(const f16x8*)&sA1[row * 64 + ((c ^ (row & 7)) << 3)];
        }
        for (int nb = 0; nb < 8; ++nb) {
            int n = nb * 16 + l15;
            b[nb] = *(const f16x8*)&sW1[n * 64 + ((c ^ (n & 7)) << 3)];
        }
        for (int mbl = 0; mbl < 2; ++mbl)
            for (int nb = 0; nb < 8; ++nb)
                acc[mbl][nb] = __builtin_amdgcn_mfma_f32_16x16x32_f16(
                    a[mbl], b[nb], acc[mbl][nb], 0, 0, 0);
    }
    __syncthreads();   // done reading sA1/sW1 before sT overlays

    // ---- epilogue1: t = swish(x1 + bf1) -> sT ----
    for (int mbl = 0; mbl < 2; ++mbl)
        for (int nb = 0; nb < 8; ++nb)
            for (int r = 0; r < 4; ++r) {
                float x = acc[mbl][nb][r] + b1v[nb];
                float tt = x / (1.0f + __expf(-x));
                int row = wv * 32 + mbl * 16 + q * 4 + r;
                int col = nb * 16 + l15;
                sT[row * 128 + (((col >> 3) ^ (row & 7)) << 3) + (col & 7)] = (_Float16)tt;
            }
    __syncthreads();

    // ---- GEMM2: [32 x 128] x [128 x 128] per wave ----
    for (int mbl = 0; mbl < 2; ++mbl)
        for (int nb = 0; nb < 8; ++nb) acc[mbl][nb] = (f32x4){0.f, 0.f, 0.f, 0.f};
    for (int ks = 0; ks < 4; ++ks) {
        f16x8 a[2], b[8];
        const int c = ks * 4 + q;
        for (int mbl = 0; mbl < 2; ++mbl) {
            int row = wv * 32 + mbl * 16 + l15;
            a[mbl] = *(const f16x8*)&sT[row * 128 + ((c ^ (row & 7)) << 3)];
        }
        for (int nb = 0; nb < 8; ++nb) {
            int n = nb * 16 + l15;
            b[nb] = *(const f16x8*)&sW2[n * 128 + ((c ^ (n & 7)) << 3)];
        }
        for (int mbl = 0; mbl < 2; ++mbl)
            for (int nb = 0; nb < 8; ++nb)
                acc[mbl][nb] = __builtin_amdgcn_mfma_f32_16x16x32_f16(
                    a[mbl], b[nb], acc[mbl][nb], 0, 0, 0);
    }
    __syncthreads();   // all waves done with sT/sW2 before sM overlays

    // ---- epilogue2: m = hv[src]*(he+bf2)*C -> sM (swizzled fp32) ----
    for (int mbl = 0; mbl < 2; ++mbl)
        for (int r = 0; r < 4; ++r) {
            int i8 = mbl * 4 + r;
            float Cr = C8[i8];
            int sb = s8[i8];
            int rowl = wv * 32 + mbl * 16 + q * 4 + r;
            for (int nb = 0; nb < 8; ++nb) {
                int col = nb * 16 + l15;
                float he = (acc[mbl][nb][r] + b2v[nb]) * Cr;
                float m = (float)hvh[sb + col] * he;
                sM[rowl * 128 + ((((col >> 2) ^ (rowl & 7)) << 2) | (col & 3))] = m;
            }
        }
    __syncthreads();

    // ---- segmented run-reduction per column (dst sorted -> runs) ----
    {
        const int col = tid & 127;
        const int half = tid >> 7;
        const int r0 = half * 64;
        float run = 0.0f;
        int cur = sMeta[r0].z;
        for (int r = r0; r < r0 + 64; ++r) {
            int d = sMeta[r].z;                // wave-uniform
            if (d != cur) {                    // wave-uniform branch
                atomicAdd(&agg[cur * 128 + col], run);
                run = 0.0f; cur = d;
            }
            run += sM[r * 128 + ((((col >> 2) ^ (r & 7)) << 2) | (col & 3))];
        }
        atomicAdd(&agg[cur * 128 + col], run);
    }
}

// ---------------------------------------------------------------------------
// out_kernel (fp32): out = swish(agg @ Wm1 + bm1) @ Wm2 + bm2, fused.
// ---------------------------------------------------------------------------
__global__ __launch_bounds__(256) void out_kernel(const float* __restrict__ agg,
                                                  const float* __restrict__ Wm1,
                                                  const float* __restrict__ bm1,
                                                  const float* __restrict__ Wm2,
                                                  const float* __restrict__ bm2,
                                                  float* __restrict__ out) {
    __shared__ float sAT[128 * 20];
    __shared__ float sTT[128 * 20];
    const int tid = threadIdx.x;
    const int row0 = blockIdx.x * 16;
    for (int t = 0; t < 8; ++t) {
        int flat = tid + 256 * t;
        int rr = flat >> 7, k = flat & 127;
        sAT[k * 20 + rr] = agg[(row0 + rr) * 128 + k];
    }
    __syncthreads();
    const int c = tid & 127, rh = tid >> 7;
    float acc[8] = {0, 0, 0, 0, 0, 0, 0, 0};
    for (int k = 0; k < 128; ++k) {
        float wval = Wm1[k * 128 + c];
        const float4 alo = *(const float4*)&sAT[k * 20 + rh * 8];
        const float4 ahi = *(const float4*)&sAT[k * 20 + rh * 8 + 4];
        acc[0] += alo.x * wval; acc[1] += alo.y * wval;
        acc[2] += alo.z * wval; acc[3] += alo.w * wval;
        acc[4] += ahi.x * wval; acc[5] += ahi.y * wval;
        acc[6] += ahi.z * wval; acc[7] += ahi.w * wval;
    }
    float bm1c = bm1[c];
    for (int r = 0; r < 8; ++r) {
        float x = acc[r] + bm1c;
        sTT[c * 20 + rh * 8 + r] = x / (1.0f + __expf(-x));
    }
    __syncthreads();
    float acc2[8] = {0, 0, 0, 0, 0, 0, 0, 0};
    for (int k = 0; k < 128; ++k) {
        float wval = Wm2[k * 128 + c];
        const float4 alo = *(const float4*)&sTT[k * 20 + rh * 8];
        const float4 ahi = *(const float4*)&sTT[k * 20 + rh * 8 + 4];
        acc2[0] += alo.x * wval; acc2[1] += alo.y * wval;
        acc2[2] += alo.z * wval; acc2[3] += alo.w * wval;
        acc2[4] += ahi.x * wval; acc2[5] += ahi.y * wval;
        acc2[6] += ahi.z * wval; acc2[7] += ahi.w * wval;
    }
    float bm2c = bm2[c];
    for (int r = 0; r < 8; ++r)
        out[(row0 + rh * 8 + r) * 128 + c] = acc2[r] + bm2c;
}

// ---------------------------------------------------------------------------
extern "C" void kernel_launch(void* const* d_in, const int* in_sizes, int n_in,
                              void* d_out, int out_size, void* d_ws, size_t ws_size,
                              hipStream_t stream) {
    const float* feat   = (const float*)d_in[0];
    const float* fij    = (const float*)d_in[1];
    const float* rij    = (const float*)d_in[2];
    const int*   srcv   = (const int*)d_in[3];
    const int*   dstv   = (const int*)d_in[4];
    const float* W_in2f = (const float*)d_in[5];
    const float* Wf1    = (const float*)d_in[6];
    const float* bf1    = (const float*)d_in[7];
    const float* Wf2    = (const float*)d_in[8];
    const float* bf2    = (const float*)d_in[9];
    const float* Wm1    = (const float*)d_in[10];
    const float* bm1    = (const float*)d_in[11];
    const float* Wm2    = (const float*)d_in[12];
    const float* bm2    = (const float*)d_in[13];
    float* out = (float*)d_out;

    char* ws = (char*)d_ws;
    float*    agg   = (float*)ws;                           // 25,600,000
    _Float16* hvh   = (_Float16*)(ws + 25600000);           // 12,800,000
    int4*     meta  = (int4*)(ws + 38400000);               // 25,600,000
    int*      cnt   = (int*)(ws + 64000000);                //    200,192
    _Float16* W1img = (_Float16*)(ws + 64200192);           //     16,384
    _Float16* W2img = (_Float16*)(ws + 64216576);           //     32,768

    hipMemsetAsync(agg, 0, (size_t)N_NODES * 128 * sizeof(float), stream);
    hipMemsetAsync(cnt, 0, (size_t)N_NODES * sizeof(int), stream);
    prep_weights<<<64, 256, 0, stream>>>(Wf1, Wf2, W1img, W2img);
    hv_kernel<<<3125, 256, 0, stream>>>(feat, W_in2f, hvh);
    hist_kernel<<<(N_EDGES + 255) / 256, 256, 0, stream>>>(dstv, cnt);
    scan_kernel<<<1, 1024, 0, stream>>>(cnt);
    scatter_kernel<<<(N_EDGES + 255) / 256, 256, 0, stream>>>(dstv, srcv, rij, cnt, meta);
    edge_kernel<<<12500, 256, 0, stream>>>(fij, hvh, W1img, W2img, bf1, bf2, meta, agg);
    out_kernel<<<3125, 256, 0, stream>>>(agg, Wm1, bm1, Wm2, bm2, out);
}

// Round 3
// 1179.891 us; speedup vs baseline: 1.3917x; 1.2557x over previous
//
#include <hip/hip_runtime.h>

#define N_NODES 50000
#define N_EDGES 1600000

typedef _Float16 f16x8 __attribute__((ext_vector_type(8)));
typedef float f32x4 __attribute__((ext_vector_type(4)));

// ---------------------------------------------------------------------------
// prep_weights: f16 weight images, transposed ([n][k]) and 16B-chunk
// XOR-swizzled (chunk' = chunk ^ (n&7)).
// W1img: [128 n][64 k] (Wf1 50x128, K zero-padded to 64).  W2img: [128][128].
// ---------------------------------------------------------------------------
__global__ void prep_weights(const float* __restrict__ Wf1,
                             const float* __restrict__ Wf2,
                             _Float16* __restrict__ W1img,
                             _Float16* __restrict__ W2img) {
    int i = blockIdx.x * 256 + threadIdx.x;
    if (i < 8192) {
        int n = i >> 6, k = i & 63;
        float v = (k < 50) ? Wf1[k * 128 + n] : 0.0f;
        W1img[n * 64 + (((k >> 3) ^ (n & 7)) << 3) + (k & 7)] = (_Float16)v;
    }
    if (i < 16384) {
        int n = i >> 7, k = i & 127;
        W2img[n * 128 + (((k >> 3) ^ (n & 7)) << 3) + (k & 7)] =
            (_Float16)Wf2[k * 128 + n];
    }
}

// ---------------------------------------------------------------------------
// Counting sort by dst: hist -> 3-kernel shuffle scan -> scatter.
// ---------------------------------------------------------------------------
__global__ void hist_kernel(const int* __restrict__ dstv, int* __restrict__ cnt) {
    int e = blockIdx.x * 256 + threadIdx.x;
    if (e < N_EDGES) atomicAdd(&cnt[dstv[e]], 1);
}

__global__ __launch_bounds__(1024) void scan_reduce(const int* __restrict__ cnt,
                                                    int* __restrict__ bsum) {
    __shared__ int ws[16];
    int tid = threadIdx.x, lane = tid & 63;
    int i = blockIdx.x * 1024 + tid;
    int x = (i < N_NODES) ? cnt[i] : 0;
    for (int o = 32; o > 0; o >>= 1) x += __shfl_down(x, o);
    if (lane == 0) ws[tid >> 6] = x;
    __syncthreads();
    if (tid == 0) {
        int s = 0;
        for (int w = 0; w < 16; ++w) s += ws[w];
        bsum[blockIdx.x] = s;
    }
}

__global__ void scan_top(int* __restrict__ bsum) {   // 49 block sums, serial
    if (threadIdx.x == 0) {
        int s = 0;
        for (int b = 0; b < 49; ++b) { int v = bsum[b]; bsum[b] = s; s += v; }
    }
}

__global__ __launch_bounds__(1024) void scan_apply(int* __restrict__ cnt,
                                                   const int* __restrict__ bsum) {
    __shared__ int ws[16], wo[16];
    int tid = threadIdx.x, lane = tid & 63, wid = tid >> 6;
    int i = blockIdx.x * 1024 + tid;
    int x = (i < N_NODES) ? cnt[i] : 0;
    int incl = x;
    for (int o = 1; o < 64; o <<= 1) {
        int y = __shfl_up(incl, o);
        if (lane >= o) incl += y;
    }
    if (lane == 63) ws[wid] = incl;
    __syncthreads();
    if (tid == 0) {
        int s = 0;
        for (int w = 0; w < 16; ++w) { wo[w] = s; s += ws[w]; }
    }
    __syncthreads();
    if (i < N_NODES) cnt[i] = bsum[blockIdx.x] + wo[wid] + incl - x;  // exclusive
}

__global__ void scatter_kernel(const int* __restrict__ dstv,
                               const int* __restrict__ srcv,
                               const float* __restrict__ rij,
                               int* __restrict__ cursor,
                               int4* __restrict__ meta) {
    int e = blockIdx.x * 256 + threadIdx.x;
    if (e < N_EDGES) {
        int d = dstv[e];
        int pos = atomicAdd(&cursor[d], 1);
        meta[pos] = make_int4(e, srcv[e], d, __float_as_int(rij[e]));
    }
}

// ---------------------------------------------------------------------------
// hv_kernel (fp32 compute, f16 store): hv = feat @ W_in2f.
// ---------------------------------------------------------------------------
__global__ __launch_bounds__(256) void hv_kernel(const float* __restrict__ feat,
                                                 const float* __restrict__ W,
                                                 _Float16* __restrict__ hvh) {
    __shared__ float sAT[128 * 20];
    const int tid = threadIdx.x;
    const int row0 = blockIdx.x * 16;
    for (int t = 0; t < 8; ++t) {
        int flat = tid + 256 * t;
        int rr = flat >> 7, k = flat & 127;
        sAT[k * 20 + rr] = feat[(row0 + rr) * 128 + k];
    }
    __syncthreads();
    const int c = tid & 127, rh = tid >> 7;
    float acc[8] = {0, 0, 0, 0, 0, 0, 0, 0};
    for (int k = 0; k < 128; ++k) {
        float wval = W[k * 128 + c];
        const float4 alo = *(const float4*)&sAT[k * 20 + rh * 8];
        const float4 ahi = *(const float4*)&sAT[k * 20 + rh * 8 + 4];
        acc[0] += alo.x * wval; acc[1] += alo.y * wval;
        acc[2] += alo.z * wval; acc[3] += alo.w * wval;
        acc[4] += ahi.x * wval; acc[5] += ahi.y * wval;
        acc[6] += ahi.z * wval; acc[7] += ahi.w * wval;
    }
    for (int r = 0; r < 8; ++r)
        hvh[(row0 + rh * 8 + r) * 128 + c] = (_Float16)acc[r];
}

// ---------------------------------------------------------------------------
// edge_kernel, 512 threads (8 waves x 16 rows), dst-sorted edges.
//   A-frags of GEMM1 loaded global->regs in MFMA layout (no sA1 staging).
//   GEMM1 -> swish -> sT (LDS) -> GEMM2 -> he*C -> sM (f16) ->
//   column-threaded segmented run-reduction with coalesced hv gather.
// LDS: R0[0,16K): sW1 then sT rows 0-63; R1[16K,48K): sW2; R2[48K,64K): sT
//      rows 64-127; sM f16 [128][132] overlays [16K, 49K) in phase C. 64 KB.
// MFMA 16x16x32_f16 layouts (verified): A: m=lane&15, k=(lane>>4)*8+j;
//   D: row=(lane>>4)*4+r, col=lane&15.
// ---------------------------------------------------------------------------
__global__ __launch_bounds__(512, 4) void edge_kernel(
        const float* __restrict__ fij, const _Float16* __restrict__ hvh,
        const _Float16* __restrict__ W1img, const _Float16* __restrict__ W2img,
        const float* __restrict__ bf1, const float* __restrict__ bf2,
        const int4* __restrict__ meta, float* __restrict__ agg) {
    __shared__ __align__(16) char smem[65536];
    __shared__ __align__(16) int4 sMeta[128];
    _Float16* sW1 = (_Float16*)smem;              // [128][64]   phase A
    _Float16* sW2 = (_Float16*)(smem + 16384);    // [128][128]  phases A-B
    _Float16* sT0 = (_Float16*)smem;              // sT rows 0-63
    _Float16* sT1 = (_Float16*)(smem + 49152);    // sT rows 64-127
    _Float16* sM  = (_Float16*)(smem + 16384);    // [128][132] f16, phase C

    const int tid = threadIdx.x;
    const int lane = tid & 63;
    const int wv = tid >> 6;          // 0..7 -> rows [wv*16, wv*16+16)
    const int l15 = lane & 15;
    const int q = lane >> 4;
    const int e0 = blockIdx.x * 128;

    // ---- early: this lane's A-frag row + direct global->reg fij loads ----
    const int arow = wv * 16 + l15;
    const int eid = meta[e0 + arow].x;
    const float* frow = fij + (long)eid * 50;
    // ks=0: k = q*8 + j (< 32, always valid); 8B-aligned float2 loads
    float2 p0 = *(const float2*)(frow + q * 8 + 0);
    float2 p1 = *(const float2*)(frow + q * 8 + 2);
    float2 p2 = *(const float2*)(frow + q * 8 + 4);
    float2 p3 = *(const float2*)(frow + q * 8 + 6);
    // ks=1: k = 32 + q*8 + j; pairs never straddle the k=50 cut (50 even)
    const int kb = 32 + q * 8;
    float2 z2 = make_float2(0.f, 0.f);
    float2 p4 = (kb + 1 < 50) ? *(const float2*)(frow + kb + 0) : z2;
    float2 p5 = (kb + 3 < 50) ? *(const float2*)(frow + kb + 2) : z2;
    float2 p6 = (kb + 5 < 50) ? *(const float2*)(frow + kb + 4) : z2;
    float2 p7 = (kb + 7 < 50) ? *(const float2*)(frow + kb + 6) : z2;
    f16x8 a0, a1;
    a0[0] = (_Float16)p0.x; a0[1] = (_Float16)p0.y;
    a0[2] = (_Float16)p1.x; a0[3] = (_Float16)p1.y;
    a0[4] = (_Float16)p2.x; a0[5] = (_Float16)p2.y;
    a0[6] = (_Float16)p3.x; a0[7] = (_Float16)p3.y;
    a1[0] = (_Float16)p4.x; a1[1] = (_Float16)p4.y;
    a1[2] = (_Float16)p5.x; a1[3] = (_Float16)p5.y;
    a1[4] = (_Float16)p6.x; a1[5] = (_Float16)p6.y;
    a1[6] = (_Float16)p7.x; a1[7] = (_Float16)p7.y;

    // ---- stage sMeta + weight images ----
    if (tid < 128) sMeta[tid] = meta[e0 + tid];
    {
        const float4* s1 = (const float4*)W1img;   // 1024 f4
        float4* d1 = (float4*)sW1;
        d1[tid] = s1[tid]; d1[tid + 512] = s1[tid + 512];
        const float4* s2 = (const float4*)W2img;   // 2048 f4
        float4* d2 = (float4*)sW2;
        for (int t = 0; t < 4; ++t) d2[tid + 512 * t] = s2[tid + 512 * t];
    }
    float b1v[8], b2v[8];
    for (int nb = 0; nb < 8; ++nb) {
        b1v[nb] = bf1[nb * 16 + l15];
        b2v[nb] = bf2[nb * 16 + l15];
    }
    __syncthreads();

    // ---- GEMM1: [16 x 64] x [64 x 128] per wave, A from regs ----
    f32x4 acc[8];
    for (int nb = 0; nb < 8; ++nb) acc[nb] = (f32x4){0.f, 0.f, 0.f, 0.f};
    {
        f16x8 b[8];
        for (int nb = 0; nb < 8; ++nb) {
            int n = nb * 16 + l15;
            b[nb] = *(const f16x8*)&sW1[n * 64 + ((q ^ (n & 7)) << 3)];
        }
        for (int nb = 0; nb < 8; ++nb)
            acc[nb] = __builtin_amdgcn_mfma_f32_16x16x32_f16(a0, b[nb], acc[nb], 0, 0, 0);
        for (int nb = 0; nb < 8; ++nb) {
            int n = nb * 16 + l15;
            b[nb] = *(const f16x8*)&sW1[n * 64 + (((4 + q) ^ (n & 7)) << 3)];
        }
        for (int nb = 0; nb < 8; ++nb)
            acc[nb] = __builtin_amdgcn_mfma_f32_16x16x32_f16(a1, b[nb], acc[nb], 0, 0, 0);
    }
    __syncthreads();   // sW1 dead -> sT overlays R0 (+R2)

    // ---- epilogue1: t = swish(x1 + bf1) -> sT (swizzled) ----
    for (int nb = 0; nb < 8; ++nb)
        for (int r = 0; r < 4; ++r) {
            float x = acc[nb][r] + b1v[nb];
            float tt = x / (1.0f + __expf(-x));
            int row = wv * 16 + q * 4 + r;
            int col = nb * 16 + l15;
            _Float16* base = (row < 64) ? sT0 + row * 128 : sT1 + (row - 64) * 128;
            base[(((col >> 3) ^ (row & 7)) << 3) + (col & 7)] = (_Float16)tt;
        }
    __syncthreads();

    // ---- GEMM2: [16 x 128] x [128 x 128] per wave ----
    for (int nb = 0; nb < 8; ++nb) acc[nb] = (f32x4){0.f, 0.f, 0.f, 0.f};
    {
        const int row = wv * 16 + l15;
        const _Float16* abase = (row < 64) ? sT0 + row * 128 : sT1 + (row - 64) * 128;
        for (int ks = 0; ks < 4; ++ks) {
            int c = ks * 4 + q;
            f16x8 a = *(const f16x8*)&abase[(c ^ (row & 7)) << 3];
            for (int nb = 0; nb < 8; ++nb) {
                int n = nb * 16 + l15;
                f16x8 b = *(const f16x8*)&sW2[n * 128 + ((c ^ (n & 7)) << 3)];
                acc[nb] = __builtin_amdgcn_mfma_f32_16x16x32_f16(a, b, acc[nb], 0, 0, 0);
            }
        }
    }
    __syncthreads();   // sT, sW2 dead -> sM overlays [16K, 49K)

    // ---- epilogue2: he = (x2+bf2)*C -> sM f16, row stride 132 (bank-safe) --
    for (int r = 0; r < 4; ++r) {
        int row = wv * 16 + q * 4 + r;
        float rv = __int_as_float(sMeta[row].w);
        float Cr = (rv < 5.0f) ? 0.5f * (__cosf(0.6283185307179586f * rv) + 1.0f) : 0.0f;
        for (int nb = 0; nb < 8; ++nb) {
            int col = nb * 16 + l15;
            sM[row * 132 + col] = (_Float16)((acc[nb][r] + b2v[nb]) * Cr);
        }
    }
    __syncthreads();

    // ---- reduction: 4 segs x 32 rows x 128 cols; coalesced hv gather ----
    {
        const int col = tid & 127;
        const int seg = tid >> 7;
        const int r0 = seg * 32;
        float run = 0.0f;
        int cur = sMeta[r0].z;
        for (int r = r0; r < r0 + 32; ++r) {
            int d = sMeta[r].z;                 // wave-uniform broadcast
            if (d != cur) {                     // wave-uniform branch
                atomicAdd(&agg[cur * 128 + col], run);
                run = 0.0f; cur = d;
            }
            float hvv = (float)hvh[(long)sMeta[r].y * 128 + col];  // coalesced
            run += hvv * (float)sM[r * 132 + col];
        }
        atomicAdd(&agg[cur * 128 + col], run);
    }
}

// ---------------------------------------------------------------------------
// out_kernel (fp32): out = swish(agg @ Wm1 + bm1) @ Wm2 + bm2, fused.
// ---------------------------------------------------------------------------
__global__ __launch_bounds__(256) void out_kernel(const float* __restrict__ agg,
                                                  const float* __restrict__ Wm1,
                                                  const float* __restrict__ bm1,
                                                  const float* __restrict__ Wm2,
                                                  const float* __restrict__ bm2,
                                                  float* __restrict__ out) {
    __shared__ float sAT[128 * 20];
    __shared__ float sTT[128 * 20];
    const int tid = threadIdx.x;
    const int row0 = blockIdx.x * 16;
    for (int t = 0; t < 8; ++t) {
        int flat = tid + 256 * t;
        int rr = flat >> 7, k = flat & 127;
        sAT[k * 20 + rr] = agg[(row0 + rr) * 128 + k];
    }
    __syncthreads();
    const int c = tid & 127, rh = tid >> 7;
    float acc[8] = {0, 0, 0, 0, 0, 0, 0, 0};
    for (int k = 0; k < 128; ++k) {
        float wval = Wm1[k * 128 + c];
        const float4 alo = *(const float4*)&sAT[k * 20 + rh * 8];
        const float4 ahi = *(const float4*)&sAT[k * 20 + rh * 8 + 4];
        acc[0] += alo.x * wval; acc[1] += alo.y * wval;
        acc[2] += alo.z * wval; acc[3] += alo.w * wval;
        acc[4] += ahi.x * wval; acc[5] += ahi.y * wval;
        acc[6] += ahi.z * wval; acc[7] += ahi.w * wval;
    }
    float bm1c = bm1[c];
    for (int r = 0; r < 8; ++r) {
        float x = acc[r] + bm1c;
        sTT[c * 20 + rh * 8 + r] = x / (1.0f + __expf(-x));
    }
    __syncthreads();
    float acc2[8] = {0, 0, 0, 0, 0, 0, 0, 0};
    for (int k = 0; k < 128; ++k) {
        float wval = Wm2[k * 128 + c];
        const float4 alo = *(const float4*)&sTT[k * 20 + rh * 8];
        const float4 ahi = *(const float4*)&sTT[k * 20 + rh * 8 + 4];
        acc2[0] += alo.x * wval; acc2[1] += alo.y * wval;
        acc2[2] += alo.z * wval; acc2[3] += alo.w * wval;
        acc2[4] += ahi.x * wval; acc2[5] += ahi.y * wval;
        acc2[6] += ahi.z * wval; acc2[7] += ahi.w * wval;
    }
    float bm2c = bm2[c];
    for (int r = 0; r < 8; ++r)
        out[(row0 + rh * 8 + r) * 128 + c] = acc2[r] + bm2c;
}

// ---------------------------------------------------------------------------
extern "C" void kernel_launch(void* const* d_in, const int* in_sizes, int n_in,
                              void* d_out, int out_size, void* d_ws, size_t ws_size,
                              hipStream_t stream) {
    const float* feat   = (const float*)d_in[0];
    const float* fij    = (const float*)d_in[1];
    const float* rij    = (const float*)d_in[2];
    const int*   srcv   = (const int*)d_in[3];
    const int*   dstv   = (const int*)d_in[4];
    const float* W_in2f = (const float*)d_in[5];
    const float* Wf1    = (const float*)d_in[6];
    const float* bf1    = (const float*)d_in[7];
    const float* Wf2    = (const float*)d_in[8];
    const float* bf2    = (const float*)d_in[9];
    const float* Wm1    = (const float*)d_in[10];
    const float* bm1    = (const float*)d_in[11];
    const float* Wm2    = (const float*)d_in[12];
    const float* bm2    = (const float*)d_in[13];
    float* out = (float*)d_out;

    char* ws = (char*)d_ws;
    float*    agg   = (float*)ws;                           // 25,600,000 B
    _Float16* hvh   = (_Float16*)(ws + 25600000);           // 12,800,000 B
    int4*     meta  = (int4*)(ws + 38400000);               // 25,600,000 B
    int*      cnt   = (int*)(ws + 64000000);                //    200,000 B
    int*      bsum  = (int*)(ws + 64200000);                //        256 B
    _Float16* W1img = (_Float16*)(ws + 64200704);           //     16,384 B
    _Float16* W2img = (_Float16*)(ws + 64217088);           //     32,768 B

    hipMemsetAsync(agg, 0, (size_t)N_NODES * 128 * sizeof(float), stream);
    hipMemsetAsync(cnt, 0, (size_t)N_NODES * sizeof(int), stream);
    prep_weights<<<64, 256, 0, stream>>>(Wf1, Wf2, W1img, W2img);
    hv_kernel<<<3125, 256, 0, stream>>>(feat, W_in2f, hvh);
    hist_kernel<<<(N_EDGES + 255) / 256, 256, 0, stream>>>(dstv, cnt);
    scan_reduce<<<49, 1024, 0, stream>>>(cnt, bsum);
    scan_top<<<1, 64, 0, stream>>>(bsum);
    scan_apply<<<49, 1024, 0, stream>>>(cnt, bsum);
    scatter_kernel<<<(N_EDGES + 255) / 256, 256, 0, stream>>>(dstv, srcv, rij, cnt, meta);
    edge_kernel<<<12500, 512, 0, stream>>>(fij, hvh, W1img, W2img, bf1, bf2, meta, agg);
    out_kernel<<<3125, 256, 0, stream>>>(agg, Wm1, bm1, Wm2, bm2, out);
}